// Round 7
// baseline (1405.499 us; speedup 1.0000x reference)
//
#include <hip/hip_runtime.h>
#include <hip/hip_bf16.h>

// VQ-VAE forward, MFMA implicit-GEMM version.
// Inputs/outputs fp32 (per reference). Intermediates NHWC bf16 in d_ws.
// Conv = 9-tap implicit GEMM: D[oc][pix] += W[oc][ic] * In[pix][ic] per (tap, ic-chunk).
// MFMA 16x16x32 bf16: A[m=lane&15][k=quad*8+j], B[k=quad*8+j][n=lane&15],
//                     D: col(n)=lane&15, row(m)=quad*4+reg   (learn_hip m89/m91/m120).
//
// R7 = R6 structure at R3 register weight.
// Register model (R0..R6): VGPR_Count excludes AGPRs; (256,3) caps VGPR+AGPR ~170.
// acc(OCB=64) = 64 AGPR -> ~106 VGPR budget. R6's afrA/afrB ping-pong (+32) spilled
// (WRITE 160->411MB). Fix: per-ot weight loads (R3 form, 80 VGPR proven), keep
// gload_lds double-buffer + one barrier per phase + XCD-chunked block swizzle.
// LDS pool is full 160KB (R6: 41.5KB x 3 blocks resident) -> 3 blocks/CU here.

typedef __bf16 bf16x8 __attribute__((ext_vector_type(8)));
typedef float  floatx4 __attribute__((ext_vector_type(4)));

__device__ __forceinline__ unsigned short f2bf(float f) {
    return __builtin_bit_cast(unsigned short, __float2bfloat16(f));
}
__device__ __forceinline__ float bf2f(unsigned short u) {
    return __bfloat162float(__builtin_bit_cast(__hip_bfloat16, u));
}

__device__ __forceinline__ void gload_lds16(const void* g, void* l) {
    __builtin_amdgcn_global_load_lds(
        (const __attribute__((address_space(1))) void*)g,
        (__attribute__((address_space(3))) void*)l, 16, 0, 0);
}

// ---------------- x: NCHW fp32 -> NHWC bf16, C padded 156->160 -------------
__global__ __launch_bounds__(256) void xpose_k(const float* __restrict__ x,
                                               unsigned short* __restrict__ xn)
{
    __shared__ unsigned short t[64 * 168];   // 64 pixels x 160ch (stride 168)
    const int b = blockIdx.y;
    const int hw0 = blockIdx.x * 64;
    const int cl = threadIdx.x >> 6;         // 0..3
    const int hwl = threadIdx.x & 63;
    #pragma unroll 4
    for (int cc = 0; cc < 40; ++cc) {
        int c = cc * 4 + cl;
        float v = (c < 156) ? x[((size_t)(b * 156 + c) << 14) + hw0 + hwl] : 0.0f;
        t[hwl * 168 + c] = f2bf(v);
    }
    __syncthreads();
    for (int i = threadIdx.x; i < 64 * 20; i += 256) {
        int row = i / 20, qq = i - row * 20;
        uint4 v = *(const uint4*)(t + row * 168 + qq * 8);
        *(uint4*)(xn + ((size_t)((b << 14) + hw0 + row)) * 160 + qq * 8) = v;
    }
}

// ---------------- weight repack: fp32 -> Wrep[tap][oc][ic] bf16 ------------
__global__ __launch_bounds__(256) void repack_k(const float* __restrict__ w,
                                                unsigned short* __restrict__ wr,
                                                int Cout, int Cin, int OCP, int ICP,
                                                int trans, int n)
{
    int i = blockIdx.x * 256 + threadIdx.x;
    if (i >= n) return;
    int ic = i % ICP, rest = i / ICP;
    int oc = rest % OCP, tap = rest / OCP;
    float v = 0.0f;
    if (oc < Cout && ic < Cin) {
        // conv:  w[oc][ic][kh][kw] OIHW;  convT: w_eff[oc][ic][kh][kw]=w[ic][oc][2-kh][2-kw]
        v = trans ? w[(size_t)(ic * Cout + oc) * 9 + (8 - tap)]
                  : w[(size_t)(oc * Cin + ic) * 9 + tap];
    }
    wr[i] = f2bf(v);
}

// ---------------- zero helpers ----------------
__global__ void zero_k(float* p) { *p = 0.0f; }
__global__ __launch_bounds__(256) void zero4_k(uint4* __restrict__ p, int n4)
{
    int i = blockIdx.x * 256 + threadIdx.x;
    if (i < n4) p[i] = uint4{0, 0, 0, 0};
}

// ---------------- MFMA conv ----------------
// ICP: padded in-channels (buffer stride, mult of 32). K-chunk 32.
// OCB: oc per block (mult 16). NX: oc-blocks in grid (= OCP/OCB).
// OMODE 0: NHWC bf16 + relu; 1: NCHW bf16 + relu, oc<OUTC; 2: NCHW fp32 + sigmoid, oc<OUTC.
//
// LDS: NB buffers, each linear [chunk c 0..1295] 16B (pixel p=c>>2, slot m=c&3).
// Slot m holds k-quad q = m ^ ((p>>1)&3)  (swizzle applied on the GLOBAL source
// address; gload_lds dest is linear wave-uniform-base + lane*16, per m104/m173).
// Read at byte (p<<6) ^ (quad<<4) ^ ((p&6)<<3): uniform 2-way (free, m136).
template <int ICP, int OCB, int OMODE, int OUTC, int NX>
__global__ __launch_bounds__(256, 3) void conv_mfma(const unsigned short* __restrict__ in,
                                                    const unsigned short* __restrict__ wrep,
                                                    const float* __restrict__ bias,
                                                    void* __restrict__ outv, int OCP,
                                                    const unsigned short* __restrict__ zpad)
{
    constexpr int NOT = OCB / 16;
    constexpr int NPH = ICP / 32;
    constexpr int NB  = (NPH > 1) ? 2 : 1;
    __shared__ unsigned short tile[NB][1296 * 8];   // 20736 B per buffer

    const int tid  = threadIdx.x;
    const int lane = tid & 63, wave = tid >> 6;
    const int col  = lane & 15, quad = lane >> 4;
    const int qsh  = quad << 4;

    // XCD-chunked swizzle: HW round-robins bid%8 across the 8 XCDs; regroup so
    // consecutive LOGICAL ids (which share input tiles) sit on one XCD.
    const int cpx = gridDim.x >> 3;
    const int bid = blockIdx.x;
    const int lid = (bid & 7) * cpx + (bid >> 3);
    const int ocblk = lid % NX;
    const int tix   = (lid / NX) & 63;
    const int b     = lid / (NX * 64);
    const int h0 = (tix >> 3) << 4, w0 = (tix & 7) << 4;

    floatx4 acc[NOT][4];
    #pragma unroll
    for (int i = 0; i < NOT; ++i)
        #pragma unroll
        for (int r = 0; r < 4; ++r) acc[i][r] = floatx4{0.f, 0.f, 0.f, 0.f};

    // per-thread source offsets for gload_lds slots s=0..4 (chunk c = tid + s*256)
    int goff[5];
    #pragma unroll
    for (int s = 0; s < 5; ++s) {
        int c = tid + (s << 8);
        int p = c >> 2, m = c & 3;
        int q = m ^ ((p >> 1) & 3);           // source-side swizzle
        int pr = p / 18, pc = p - pr * 18;
        int gh = h0 - 1 + pr, gw = w0 - 1 + pc;
        bool ok = ((unsigned)gh < 128u) & ((unsigned)gw < 128u);
        goff[s] = ok ? ((((b << 7) + gh) << 7) + gw) * ICP + (q << 3) : -1;
    }

    auto stage = [&](int bufi, int icc) {
        // 5 full-wave gload_lds rounds: chunks 0..1279, linear dest
        unsigned short* base = &tile[bufi][wave * 512];   // (wave*64 chunks)*8 shorts
        #pragma unroll
        for (int s = 0; s < 5; ++s) {
            const unsigned short* src =
                (goff[s] >= 0) ? in + (size_t)goff[s] + icc * 32 : zpad;
            gload_lds16(src, base + s * 2048);            // (s*256 chunks)*8 shorts
        }
        // tail: chunks 1280..1295 (pixels 320..323 = row 17, cols 14..17)
        if (tid < 16) {
            int c = 1280 + tid;
            int p = c >> 2, m = c & 3;
            int q = m ^ ((p >> 1) & 3);
            int pc = p - 306;                              // p/18 == 17
            int gh = h0 + 16, gw = w0 - 1 + pc;
            uint4 v = uint4{0, 0, 0, 0};
            if ((unsigned)gh < 128u && (unsigned)gw < 128u)
                v = *(const uint4*)(in +
                    (size_t)((((b << 7) + gh) << 7) + gw) * ICP + icc * 32 + (q << 3));
            *(uint4*)(&tile[bufi][c << 3]) = v;
        }
    };

    auto compute_ph = [&](int bufi, int icc) {
        const unsigned short* tb = &tile[bufi][0];
        #pragma unroll
        for (int tap = 0; tap < 9; ++tap) {
            const int dh = tap / 3, dw = tap % 3;
            bf16x8 bfr[4];
            #pragma unroll
            for (int rt = 0; rt < 4; ++rt) {
                int p = ((wave << 2) + rt + dh) * 18 + col + dw;
                int boff = (p << 6) ^ qsh ^ ((p & 6) << 3);
                bfr[rt] = *(const bf16x8*)((const char*)tb + boff);
            }
            #pragma unroll
            for (int ot = 0; ot < NOT; ++ot) {
                int oc = ocblk * OCB + (ot << 4) + col;
                bf16x8 afr = *(const bf16x8*)(wrep +
                    ((size_t)(tap * OCP + oc)) * ICP + icc * 32 + (quad << 3));
                #pragma unroll
                for (int rt = 0; rt < 4; ++rt)
                    acc[ot][rt] = __builtin_amdgcn_mfma_f32_16x16x32_bf16(
                        afr, bfr[rt], acc[ot][rt], 0, 0, 0);
            }
        }
    };

    // ---- pipeline: stage(0); drain; barrier; { stage(next); compute(cur); barrier } ----
    stage(0, 0);
    asm volatile("s_waitcnt vmcnt(0)" ::: "memory");
    __syncthreads();
    #pragma unroll
    for (int icc = 0; icc < NPH; ++icc) {
        const int cur = icc & 1;
        if (icc + 1 < NPH) stage(cur ^ 1, icc + 1);   // async into other buffer
        compute_ph(cur, icc);                         // hides staging latency
        if (icc + 1 < NPH) __syncthreads();           // drains vmcnt (cheap by now)
    }

    // epilogue. D: col=pixel w, row m = quad*4+reg = oc_local
    const int w = w0 + col;
    #pragma unroll
    for (int ot = 0; ot < NOT; ++ot) {
        int oc0 = ocblk * OCB + (ot << 4) + (quad << 2);
        #pragma unroll
        for (int rt = 0; rt < 4; ++rt) {
            int h = h0 + (wave << 2) + rt;
            if constexpr (OMODE == 0) {
                unsigned short* outp = (unsigned short*)outv;
                unsigned short pk[4];
                #pragma unroll
                for (int g = 0; g < 4; ++g) {
                    float vv = acc[ot][rt][g] + bias[oc0 + g];
                    pk[g] = f2bf(fmaxf(vv, 0.0f));
                }
                size_t off = ((size_t)(((b << 7) + h) << 7) + w) * OUTC + oc0;
                *(uint2*)(outp + off) = *(const uint2*)pk;   // 4 consecutive oc, 8B
            } else if constexpr (OMODE == 1) {
                unsigned short* outp = (unsigned short*)outv;
                #pragma unroll
                for (int g = 0; g < 4; ++g) {
                    int oc = oc0 + g;
                    if (oc < OUTC) {
                        float vv = fmaxf(acc[ot][rt][g] + bias[oc], 0.0f);
                        outp[((size_t)(b * OUTC + oc) << 14) + (h << 7) + w] = f2bf(vv);
                    }
                }
            } else {
                float* outp = (float*)outv;
                #pragma unroll
                for (int g = 0; g < 4; ++g) {
                    int oc = oc0 + g;
                    if (oc < OUTC) {
                        float vv = acc[ot][rt][g] + bias[oc];
                        vv = 1.0f / (1.0f + __expf(-vv));
                        outp[((size_t)(b * OUTC + oc) << 14) + (h << 7) + w] = vv;
                    }
                }
            }
        }
    }
}

// ---------------- vector quantizer ----------------
// z3: NCHW bf16 [16,8,128,128]; rows = 8 consecutive flat elements (= 8 w-pixels, one channel).
__global__ __launch_bounds__(256) void vq_k(const unsigned short* __restrict__ z,
                                            const float* __restrict__ emb,
                                            unsigned short* __restrict__ q,
                                            float* __restrict__ loss)
{
    __shared__ float se[512 * 8];
    __shared__ float se2[512];
    __shared__ float red[4];

    for (int i = threadIdx.x; i < 4096; i += 256) se[i] = emb[i];
    __syncthreads();
    for (int k = threadIdx.x; k < 512; k += 256) {
        float s = 0.0f;
        #pragma unroll
        for (int j = 0; j < 8; ++j) { float e = se[k * 8 + j]; s += e * e; }
        se2[k] = s;
    }
    __syncthreads();

    int r = blockIdx.x * 256 + threadIdx.x;   // grid sized exactly 262144
    uint4 raw = *(const uint4*)(z + (size_t)r * 8);
    const unsigned short* pr = (const unsigned short*)&raw;
    float zv[8];
    #pragma unroll
    for (int j = 0; j < 8; ++j) zv[j] = bf2f(pr[j]);

    float best = 3.4e38f;
    int bi = 0;
    for (int k = 0; k < 512; ++k) {
        float dot = 0.0f;
        #pragma unroll
        for (int j = 0; j < 8; ++j) dot += se[k * 8 + j] * zv[j];
        float d = se2[k] - 2.0f * dot;
        if (d < best) { best = d; bi = k; }   // strict <: first-min argmin
    }

    // r = ((b*8+c)*128 + h)*16 + wg
    int wg = r & 15, h = (r >> 4) & 127, c = (r >> 11) & 7, b = r >> 14;
    size_t pixbase = ((size_t)(((b << 7) + h) << 7)) + (wg << 3);
    float lsum = 0.0f;
    #pragma unroll
    for (int j = 0; j < 8; ++j) {
        float e = se[bi * 8 + j];
        q[(pixbase + j) * 32 + c] = f2bf(e);
        float df = e - zv[j];
        lsum += df * df;
    }

    for (int o = 32; o > 0; o >>= 1) lsum += __shfl_down(lsum, o, 64);
    int lane = threadIdx.x & 63, wv = threadIdx.x >> 6;
    if (lane == 0) red[wv] = lsum;
    __syncthreads();
    if (threadIdx.x == 0) atomicAdd(loss, red[0] + red[1] + red[2] + red[3]);
}

__global__ void fin_k(const float* __restrict__ loss, float* __restrict__ out)
{
    out[0] = 1.25f * (*loss) / 2097152.0f;
}

// ---------------- launch ----------------
extern "C" void kernel_launch(void* const* d_in, const int* in_sizes, int n_in,
                              void* d_out, int out_size, void* d_ws, size_t ws_size,
                              hipStream_t stream)
{
    const float* x   = (const float*)d_in[0];
    const float* e1w = (const float*)d_in[1];
    const float* e1b = (const float*)d_in[2];
    const float* e2w = (const float*)d_in[3];
    const float* e2b = (const float*)d_in[4];
    const float* e3w = (const float*)d_in[5];
    const float* e3b = (const float*)d_in[6];
    const float* emb = (const float*)d_in[7];
    const float* d1w = (const float*)d_in[8];
    const float* d1b = (const float*)d_in[9];
    const float* d2w = (const float*)d_in[10];
    const float* d2b = (const float*)d_in[11];
    const float* d3w = (const float*)d_in[12];
    const float* d3b = (const float*)d_in[13];
    float* out = (float*)d_out;

    char* ws = (char*)d_ws;
    size_t off = 0;
    auto alloc = [&](size_t bytes) { void* p = ws + off; off += (bytes + 255) & ~size_t(255); return p; };

    float*          loss  = (float*)alloc(4);
    unsigned short* zpad  = (unsigned short*)alloc(512);
    unsigned short* wr_e1 = (unsigned short*)alloc((size_t)9 * 128 * 160 * 2);
    unsigned short* wr_e2 = (unsigned short*)alloc((size_t)9 * 64 * 128 * 2);
    unsigned short* wr_e3 = (unsigned short*)alloc((size_t)9 * 16 * 64 * 2);
    unsigned short* wr_d1 = (unsigned short*)alloc((size_t)9 * 64 * 32 * 2);
    unsigned short* wr_d2 = (unsigned short*)alloc((size_t)9 * 128 * 64 * 2);
    unsigned short* wr_d3 = (unsigned short*)alloc((size_t)9 * 192 * 128 * 2);
    unsigned short* z3    = (unsigned short*)alloc((size_t)16 * 8 * 16384 * 2);
    unsigned short* qb    = (unsigned short*)alloc((size_t)16 * 16384 * 32 * 2);
    unsigned short* S1    = (unsigned short*)alloc((size_t)16 * 16384 * 160 * 2); // xn -> b2 -> b4
    unsigned short* S2    = (unsigned short*)alloc((size_t)16 * 16384 * 128 * 2); // b1 -> b5
    (void)ws_size;

    zero_k<<<1, 1, 0, stream>>>(loss);
    zero4_k<<<1, 256, 0, stream>>>((uint4*)zpad, 32);   // 512B zero pad for OOB gload_lds
    // zero q (padded 32-ch NHWC; channels 8..31 must be 0)
    zero4_k<<<(16 * 16384 * 32 / 8 + 255) / 256, 256, 0, stream>>>((uint4*)qb, 16 * 16384 * 32 / 8);

    xpose_k<<<dim3(256, 16), 256, 0, stream>>>(x, S1);

    auto rp = [&](const float* w, unsigned short* wr, int Cout, int Cin, int OCP, int ICP, int trans) {
        int n = 9 * OCP * ICP;
        repack_k<<<(n + 255) / 256, 256, 0, stream>>>(w, wr, Cout, Cin, OCP, ICP, trans, n);
    };
    rp(e1w, wr_e1, 128, 156, 128, 160, 0);
    rp(e2w, wr_e2,  64, 128,  64, 128, 0);
    rp(e3w, wr_e3,   8,  64,  16,  64, 0);
    rp(d1w, wr_d1,  64,   8,  64,  32, 1);
    rp(d2w, wr_d2, 128,  64, 128,  64, 1);
    rp(d3w, wr_d3, 156, 128, 192, 128, 1);

    // encoder  (ICP, OCB, OMODE, OUTC, NX); 1D grid = NX*64*16
    conv_mfma<160, 64, 0, 128, 2><<<2048, 256, 0, stream>>>(S1, wr_e1, e1b, S2, 128, zpad);
    conv_mfma<128, 64, 0,  64, 1><<<1024, 256, 0, stream>>>(S2, wr_e2, e2b, S1, 64, zpad);
    conv_mfma< 64, 16, 1,   8, 1><<<1024, 256, 0, stream>>>(S1, wr_e3, e3b, z3, 16, zpad);
    // VQ
    vq_k<<<1024, 256, 0, stream>>>(z3, emb, qb, loss);
    // decoder
    conv_mfma< 32, 64, 0,  64, 1><<<1024, 256, 0, stream>>>(qb, wr_d1, d1b, S1, 64, zpad);
    conv_mfma< 64, 64, 0, 128, 2><<<2048, 256, 0, stream>>>(S1, wr_d2, d2b, S2, 128, zpad);
    conv_mfma<128, 64, 2, 156, 3><<<3072, 256, 0, stream>>>(S2, wr_d3, d3b, out, 192, zpad);

    fin_k<<<1, 1, 0, stream>>>(loss, out + (size_t)16 * 156 * 16384);
}

// Round 8
// 1051.605 us; speedup vs baseline: 1.3365x; 1.3365x over previous
//
#include <hip/hip_runtime.h>
#include <hip/hip_bf16.h>

// VQ-VAE forward, MFMA implicit-GEMM version.
// Inputs/outputs fp32 (per reference). Intermediates NHWC bf16 in d_ws.
// Conv = 9-tap implicit GEMM: D[oc][pix] += W[oc][ic] * In[pix][ic] per (tap, ic-chunk).
// MFMA 16x16x32 bf16: A[m=lane&15][k=quad*8+j], B[k=quad*8+j][n=lane&15],
//                     D: col(n)=lane&15, row(m)=quad*4+reg   (learn_hip m89/m91/m120).
//
// R8 = R5 + async gload_lds double-buffer, spill-proof.
// Register model (R0..R7, 3x confirmed): OCB=64 demand ~192 total (128 VGPR + 64 AGPR);
// (256,3) cap ~170 ALWAYS spills acc (WRITE 160->411MB tripwire). So (256,2).
// XCD swizzle (R6/R7) hurt L2 reuse (FETCH 117->300MB): natural 3D grid restored,
// blockIdx.x = ocblk fastest -> input-sharing blocks dispatch adjacently.

typedef __bf16 bf16x8 __attribute__((ext_vector_type(8)));
typedef float  floatx4 __attribute__((ext_vector_type(4)));

__device__ __forceinline__ unsigned short f2bf(float f) {
    return __builtin_bit_cast(unsigned short, __float2bfloat16(f));
}
__device__ __forceinline__ float bf2f(unsigned short u) {
    return __bfloat162float(__builtin_bit_cast(__hip_bfloat16, u));
}

__device__ __forceinline__ void gload_lds16(const void* g, void* l) {
    __builtin_amdgcn_global_load_lds(
        (const __attribute__((address_space(1))) void*)g,
        (__attribute__((address_space(3))) void*)l, 16, 0, 0);
}

// ---------------- x: NCHW fp32 -> NHWC bf16, C padded 156->160 -------------
__global__ __launch_bounds__(256) void xpose_k(const float* __restrict__ x,
                                               unsigned short* __restrict__ xn)
{
    __shared__ unsigned short t[64 * 168];   // 64 pixels x 160ch (stride 168)
    const int b = blockIdx.y;
    const int hw0 = blockIdx.x * 64;
    const int cl = threadIdx.x >> 6;         // 0..3
    const int hwl = threadIdx.x & 63;
    #pragma unroll 4
    for (int cc = 0; cc < 40; ++cc) {
        int c = cc * 4 + cl;
        float v = (c < 156) ? x[((size_t)(b * 156 + c) << 14) + hw0 + hwl] : 0.0f;
        t[hwl * 168 + c] = f2bf(v);
    }
    __syncthreads();
    for (int i = threadIdx.x; i < 64 * 20; i += 256) {
        int row = i / 20, qq = i - row * 20;
        uint4 v = *(const uint4*)(t + row * 168 + qq * 8);
        *(uint4*)(xn + ((size_t)((b << 14) + hw0 + row)) * 160 + qq * 8) = v;
    }
}

// ---------------- weight repack: fp32 -> Wrep[tap][oc][ic] bf16 ------------
__global__ __launch_bounds__(256) void repack_k(const float* __restrict__ w,
                                                unsigned short* __restrict__ wr,
                                                int Cout, int Cin, int OCP, int ICP,
                                                int trans, int n)
{
    int i = blockIdx.x * 256 + threadIdx.x;
    if (i >= n) return;
    int ic = i % ICP, rest = i / ICP;
    int oc = rest % OCP, tap = rest / OCP;
    float v = 0.0f;
    if (oc < Cout && ic < Cin) {
        // conv:  w[oc][ic][kh][kw] OIHW;  convT: w_eff[oc][ic][kh][kw]=w[ic][oc][2-kh][2-kw]
        v = trans ? w[(size_t)(ic * Cout + oc) * 9 + (8 - tap)]
                  : w[(size_t)(oc * Cin + ic) * 9 + tap];
    }
    wr[i] = f2bf(v);
}

// ---------------- zero helpers ----------------
__global__ void zero_k(float* p) { *p = 0.0f; }
__global__ __launch_bounds__(256) void zero4_k(uint4* __restrict__ p, int n4)
{
    int i = blockIdx.x * 256 + threadIdx.x;
    if (i < n4) p[i] = uint4{0, 0, 0, 0};
}

// ---------------- MFMA conv ----------------
// ICP: padded in-channels (buffer stride, mult of 32). K-chunk 32.
// OCB: oc per block (mult 16).
// OMODE 0: NHWC bf16 + relu; 1: NCHW bf16 + relu, oc<OUTC; 2: NCHW fp32 + sigmoid, oc<OUTC.
//
// LDS: NB buffers, each linear [chunk c 0..1295] 16B (pixel p=c>>2, slot m=c&3).
// Slot m holds k-quad q = m ^ ((p>>1)&3)  (swizzle applied on the GLOBAL source
// address; gload_lds dest is linear wave-uniform-base + lane*16, per m104/m173).
// Read at byte (p<<6) ^ (quad<<4) ^ ((p&6)<<3): uniform 2-way (free, m136).
template <int ICP, int OCB, int OMODE, int OUTC>
__global__ __launch_bounds__(256, 2) void conv_mfma(const unsigned short* __restrict__ in,
                                                    const unsigned short* __restrict__ wrep,
                                                    const float* __restrict__ bias,
                                                    void* __restrict__ outv, int OCP,
                                                    const unsigned short* __restrict__ zpad)
{
    constexpr int NOT = OCB / 16;
    constexpr int NPH = ICP / 32;
    constexpr int NB  = (NPH > 1) ? 2 : 1;
    __shared__ unsigned short tile[NB][1296 * 8];   // 20736 B per buffer

    const int tid  = threadIdx.x;
    const int lane = tid & 63, wave = tid >> 6;
    const int col  = lane & 15, quad = lane >> 4;
    const int qsh  = quad << 4;
    const int ocblk = blockIdx.x, tix = blockIdx.y, b = blockIdx.z;
    const int h0 = (tix >> 3) << 4, w0 = (tix & 7) << 4;

    floatx4 acc[NOT][4];
    #pragma unroll
    for (int i = 0; i < NOT; ++i)
        #pragma unroll
        for (int r = 0; r < 4; ++r) acc[i][r] = floatx4{0.f, 0.f, 0.f, 0.f};

    // per-thread source offsets for gload_lds slots s=0..4 (chunk c = tid + s*256)
    int goff[5];
    #pragma unroll
    for (int s = 0; s < 5; ++s) {
        int c = tid + (s << 8);
        int p = c >> 2, m = c & 3;
        int q = m ^ ((p >> 1) & 3);           // source-side swizzle
        int pr = p / 18, pc = p - pr * 18;
        int gh = h0 - 1 + pr, gw = w0 - 1 + pc;
        bool ok = ((unsigned)gh < 128u) & ((unsigned)gw < 128u);
        goff[s] = ok ? ((((b << 7) + gh) << 7) + gw) * ICP + (q << 3) : -1;
    }

    auto stage = [&](int bufi, int icc) {
        // 5 full-wave gload_lds rounds: chunks 0..1279, linear dest
        unsigned short* base = &tile[bufi][wave * 512];   // (wave*64 chunks)*8 shorts
        #pragma unroll
        for (int s = 0; s < 5; ++s) {
            const unsigned short* src =
                (goff[s] >= 0) ? in + (size_t)goff[s] + icc * 32 : zpad;
            gload_lds16(src, base + s * 2048);            // (s*256 chunks)*8 shorts
        }
        // tail: chunks 1280..1295 (pixels 320..323 = row 17, cols 14..17)
        if (tid < 16) {
            int c = 1280 + tid;
            int p = c >> 2, m = c & 3;
            int q = m ^ ((p >> 1) & 3);
            int pc = p - 306;                              // p/18 == 17
            int gh = h0 + 16, gw = w0 - 1 + pc;
            uint4 v = uint4{0, 0, 0, 0};
            if ((unsigned)gh < 128u && (unsigned)gw < 128u)
                v = *(const uint4*)(in +
                    (size_t)((((b << 7) + gh) << 7) + gw) * ICP + icc * 32 + (q << 3));
            *(uint4*)(&tile[bufi][c << 3]) = v;
        }
    };

    auto compute_ph = [&](int bufi, int icc) {
        const unsigned short* tb = &tile[bufi][0];
        #pragma unroll
        for (int tap = 0; tap < 9; ++tap) {
            const int dh = tap / 3, dw = tap % 3;
            bf16x8 bfr[4];
            #pragma unroll
            for (int rt = 0; rt < 4; ++rt) {
                int p = ((wave << 2) + rt + dh) * 18 + col + dw;
                int boff = (p << 6) ^ qsh ^ ((p & 6) << 3);
                bfr[rt] = *(const bf16x8*)((const char*)tb + boff);
            }
            #pragma unroll
            for (int ot = 0; ot < NOT; ++ot) {
                int oc = ocblk * OCB + (ot << 4) + col;
                bf16x8 afr = *(const bf16x8*)(wrep +
                    ((size_t)(tap * OCP + oc)) * ICP + icc * 32 + (quad << 3));
                #pragma unroll
                for (int rt = 0; rt < 4; ++rt)
                    acc[ot][rt] = __builtin_amdgcn_mfma_f32_16x16x32_bf16(
                        afr, bfr[rt], acc[ot][rt], 0, 0, 0);
            }
        }
    };

    // ---- pipeline: stage(0); drain; barrier; { stage(next); compute(cur); barrier } ----
    stage(0, 0);
    asm volatile("s_waitcnt vmcnt(0)" ::: "memory");
    __syncthreads();
    #pragma unroll
    for (int icc = 0; icc < NPH; ++icc) {
        const int cur = icc & 1;
        if (icc + 1 < NPH) stage(cur ^ 1, icc + 1);   // async into other buffer
        compute_ph(cur, icc);                         // hides staging latency
        if (icc + 1 < NPH) __syncthreads();           // drains vmcnt (covered by compute)
    }

    // epilogue. D: col=pixel w, row m = quad*4+reg = oc_local
    const int w = w0 + col;
    #pragma unroll
    for (int ot = 0; ot < NOT; ++ot) {
        int oc0 = ocblk * OCB + (ot << 4) + (quad << 2);
        #pragma unroll
        for (int rt = 0; rt < 4; ++rt) {
            int h = h0 + (wave << 2) + rt;
            if constexpr (OMODE == 0) {
                unsigned short* outp = (unsigned short*)outv;
                unsigned short pk[4];
                #pragma unroll
                for (int g = 0; g < 4; ++g) {
                    float vv = acc[ot][rt][g] + bias[oc0 + g];
                    pk[g] = f2bf(fmaxf(vv, 0.0f));
                }
                size_t off = ((size_t)(((b << 7) + h) << 7) + w) * OUTC + oc0;
                *(uint2*)(outp + off) = *(const uint2*)pk;   // 4 consecutive oc, 8B
            } else if constexpr (OMODE == 1) {
                unsigned short* outp = (unsigned short*)outv;
                #pragma unroll
                for (int g = 0; g < 4; ++g) {
                    int oc = oc0 + g;
                    if (oc < OUTC) {
                        float vv = fmaxf(acc[ot][rt][g] + bias[oc], 0.0f);
                        outp[((size_t)(b * OUTC + oc) << 14) + (h << 7) + w] = f2bf(vv);
                    }
                }
            } else {
                float* outp = (float*)outv;
                #pragma unroll
                for (int g = 0; g < 4; ++g) {
                    int oc = oc0 + g;
                    if (oc < OUTC) {
                        float vv = acc[ot][rt][g] + bias[oc];
                        vv = 1.0f / (1.0f + __expf(-vv));
                        outp[((size_t)(b * OUTC + oc) << 14) + (h << 7) + w] = vv;
                    }
                }
            }
        }
    }
}

// ---------------- vector quantizer ----------------
// z3: NCHW bf16 [16,8,128,128]; rows = 8 consecutive flat elements (= 8 w-pixels, one channel).
__global__ __launch_bounds__(256) void vq_k(const unsigned short* __restrict__ z,
                                            const float* __restrict__ emb,
                                            unsigned short* __restrict__ q,
                                            float* __restrict__ loss)
{
    __shared__ float se[512 * 8];
    __shared__ float se2[512];
    __shared__ float red[4];

    for (int i = threadIdx.x; i < 4096; i += 256) se[i] = emb[i];
    __syncthreads();
    for (int k = threadIdx.x; k < 512; k += 256) {
        float s = 0.0f;
        #pragma unroll
        for (int j = 0; j < 8; ++j) { float e = se[k * 8 + j]; s += e * e; }
        se2[k] = s;
    }
    __syncthreads();

    int r = blockIdx.x * 256 + threadIdx.x;   // grid sized exactly 262144
    uint4 raw = *(const uint4*)(z + (size_t)r * 8);
    const unsigned short* pr = (const unsigned short*)&raw;
    float zv[8];
    #pragma unroll
    for (int j = 0; j < 8; ++j) zv[j] = bf2f(pr[j]);

    float best = 3.4e38f;
    int bi = 0;
    for (int k = 0; k < 512; ++k) {
        float dot = 0.0f;
        #pragma unroll
        for (int j = 0; j < 8; ++j) dot += se[k * 8 + j] * zv[j];
        float d = se2[k] - 2.0f * dot;
        if (d < best) { best = d; bi = k; }   // strict <: first-min argmin
    }

    // r = ((b*8+c)*128 + h)*16 + wg
    int wg = r & 15, h = (r >> 4) & 127, c = (r >> 11) & 7, b = r >> 14;
    size_t pixbase = ((size_t)(((b << 7) + h) << 7)) + (wg << 3);
    float lsum = 0.0f;
    #pragma unroll
    for (int j = 0; j < 8; ++j) {
        float e = se[bi * 8 + j];
        q[(pixbase + j) * 32 + c] = f2bf(e);
        float df = e - zv[j];
        lsum += df * df;
    }

    for (int o = 32; o > 0; o >>= 1) lsum += __shfl_down(lsum, o, 64);
    int lane = threadIdx.x & 63, wv = threadIdx.x >> 6;
    if (lane == 0) red[wv] = lsum;
    __syncthreads();
    if (threadIdx.x == 0) atomicAdd(loss, red[0] + red[1] + red[2] + red[3]);
}

__global__ void fin_k(const float* __restrict__ loss, float* __restrict__ out)
{
    out[0] = 1.25f * (*loss) / 2097152.0f;
}

// ---------------- launch ----------------
extern "C" void kernel_launch(void* const* d_in, const int* in_sizes, int n_in,
                              void* d_out, int out_size, void* d_ws, size_t ws_size,
                              hipStream_t stream)
{
    const float* x   = (const float*)d_in[0];
    const float* e1w = (const float*)d_in[1];
    const float* e1b = (const float*)d_in[2];
    const float* e2w = (const float*)d_in[3];
    const float* e2b = (const float*)d_in[4];
    const float* e3w = (const float*)d_in[5];
    const float* e3b = (const float*)d_in[6];
    const float* emb = (const float*)d_in[7];
    const float* d1w = (const float*)d_in[8];
    const float* d1b = (const float*)d_in[9];
    const float* d2w = (const float*)d_in[10];
    const float* d2b = (const float*)d_in[11];
    const float* d3w = (const float*)d_in[12];
    const float* d3b = (const float*)d_in[13];
    float* out = (float*)d_out;

    char* ws = (char*)d_ws;
    size_t off = 0;
    auto alloc = [&](size_t bytes) { void* p = ws + off; off += (bytes + 255) & ~size_t(255); return p; };

    float*          loss  = (float*)alloc(4);
    unsigned short* zpad  = (unsigned short*)alloc(512);
    unsigned short* wr_e1 = (unsigned short*)alloc((size_t)9 * 128 * 160 * 2);
    unsigned short* wr_e2 = (unsigned short*)alloc((size_t)9 * 64 * 128 * 2);
    unsigned short* wr_e3 = (unsigned short*)alloc((size_t)9 * 16 * 64 * 2);
    unsigned short* wr_d1 = (unsigned short*)alloc((size_t)9 * 64 * 32 * 2);
    unsigned short* wr_d2 = (unsigned short*)alloc((size_t)9 * 128 * 64 * 2);
    unsigned short* wr_d3 = (unsigned short*)alloc((size_t)9 * 192 * 128 * 2);
    unsigned short* z3    = (unsigned short*)alloc((size_t)16 * 8 * 16384 * 2);
    unsigned short* qb    = (unsigned short*)alloc((size_t)16 * 16384 * 32 * 2);
    unsigned short* S1    = (unsigned short*)alloc((size_t)16 * 16384 * 160 * 2); // xn -> b2 -> b4
    unsigned short* S2    = (unsigned short*)alloc((size_t)16 * 16384 * 128 * 2); // b1 -> b5
    (void)ws_size;

    zero_k<<<1, 1, 0, stream>>>(loss);
    zero4_k<<<1, 256, 0, stream>>>((uint4*)zpad, 32);   // 512B zero pad for OOB gload_lds
    // zero q (padded 32-ch NHWC; channels 8..31 must be 0)
    zero4_k<<<(16 * 16384 * 32 / 8 + 255) / 256, 256, 0, stream>>>((uint4*)qb, 16 * 16384 * 32 / 8);

    xpose_k<<<dim3(256, 16), 256, 0, stream>>>(x, S1);

    auto rp = [&](const float* w, unsigned short* wr, int Cout, int Cin, int OCP, int ICP, int trans) {
        int n = 9 * OCP * ICP;
        repack_k<<<(n + 255) / 256, 256, 0, stream>>>(w, wr, Cout, Cin, OCP, ICP, trans, n);
    };
    rp(e1w, wr_e1, 128, 156, 128, 160, 0);
    rp(e2w, wr_e2,  64, 128,  64, 128, 0);
    rp(e3w, wr_e3,   8,  64,  16,  64, 0);
    rp(d1w, wr_d1,  64,   8,  64,  32, 1);
    rp(d2w, wr_d2, 128,  64, 128,  64, 1);
    rp(d3w, wr_d3, 156, 128, 192, 128, 1);

    // encoder  (ICP, OCB, OMODE, OUTC); grid = (OCP/OCB, 64, 16)
    conv_mfma<160, 64, 0, 128><<<dim3(2, 64, 16), 256, 0, stream>>>(S1, wr_e1, e1b, S2, 128, zpad);
    conv_mfma<128, 64, 0,  64><<<dim3(1, 64, 16), 256, 0, stream>>>(S2, wr_e2, e2b, S1, 64, zpad);
    conv_mfma< 64, 16, 1,   8><<<dim3(1, 64, 16), 256, 0, stream>>>(S1, wr_e3, e3b, z3, 16, zpad);
    // VQ
    vq_k<<<1024, 256, 0, stream>>>(z3, emb, qb, loss);
    // decoder
    conv_mfma< 32, 64, 0,  64><<<dim3(1, 64, 16), 256, 0, stream>>>(qb, wr_d1, d1b, S1, 64, zpad);
    conv_mfma< 64, 64, 0, 128><<<dim3(2, 64, 16), 256, 0, stream>>>(S1, wr_d2, d2b, S2, 128, zpad);
    conv_mfma<128, 64, 2, 156><<<dim3(3, 64, 16), 256, 0, stream>>>(S2, wr_d3, d3b, out, 192, zpad);

    fin_k<<<1, 1, 0, stream>>>(loss, out + (size_t)16 * 156 * 16384);
}

// Round 9
// 760.874 us; speedup vs baseline: 1.8472x; 1.3821x over previous
//
#include <hip/hip_runtime.h>
#include <hip/hip_bf16.h>

// VQ-VAE forward, MFMA implicit-GEMM version.
// Inputs/outputs fp32 (per reference). Intermediates NHWC bf16 in d_ws.
// Conv = 9-tap implicit GEMM: D[oc][pix] += W[oc][ic] * In[pix][ic] per (tap, ic-chunk).
// MFMA 16x16x32 bf16: A[m=lane&15][k=quad*8+j], B[k=quad*8+j][n=lane&15],
//                     D: col(n)=lane&15, row(m)=quad*4+reg   (learn_hip m89/m91/m120).
//
// R9: weights into LDS (m97-style both-operand staging).
// R8 evidence: staging fully async yet wall ~95% idle -> the 36 per-lane global
// weight loads per wave-phase expose L2 latency inside compute. Fix: stage the
// (ocblk, icc) weight slice (9 taps x OCB x 32ch = 36.9KB @ OCB=64) into LDS via
// gload_lds, single-buffered, re-staged between barriers each phase. Inner loop
// becomes pure ds_read_b128 + MFMA. Weight LDS swizzle: slot m <-> quad
// m^((oc>>1)&3) (same 2-way-free bank pattern as the input tile; rule #21 pair:
// linear gload_lds dest + pre-swizzled global source + swizzled read).

typedef __bf16 bf16x8 __attribute__((ext_vector_type(8)));
typedef float  floatx4 __attribute__((ext_vector_type(4)));

__device__ __forceinline__ unsigned short f2bf(float f) {
    return __builtin_bit_cast(unsigned short, __float2bfloat16(f));
}
__device__ __forceinline__ float bf2f(unsigned short u) {
    return __bfloat162float(__builtin_bit_cast(__hip_bfloat16, u));
}

__device__ __forceinline__ void gload_lds16(const void* g, void* l) {
    __builtin_amdgcn_global_load_lds(
        (const __attribute__((address_space(1))) void*)g,
        (__attribute__((address_space(3))) void*)l, 16, 0, 0);
}

// ---------------- x: NCHW fp32 -> NHWC bf16, C padded 156->160 -------------
__global__ __launch_bounds__(256) void xpose_k(const float* __restrict__ x,
                                               unsigned short* __restrict__ xn)
{
    __shared__ unsigned short t[64 * 168];   // 64 pixels x 160ch (stride 168)
    const int b = blockIdx.y;
    const int hw0 = blockIdx.x * 64;
    const int cl = threadIdx.x >> 6;         // 0..3
    const int hwl = threadIdx.x & 63;
    #pragma unroll 4
    for (int cc = 0; cc < 40; ++cc) {
        int c = cc * 4 + cl;
        float v = (c < 156) ? x[((size_t)(b * 156 + c) << 14) + hw0 + hwl] : 0.0f;
        t[hwl * 168 + c] = f2bf(v);
    }
    __syncthreads();
    for (int i = threadIdx.x; i < 64 * 20; i += 256) {
        int row = i / 20, qq = i - row * 20;
        uint4 v = *(const uint4*)(t + row * 168 + qq * 8);
        *(uint4*)(xn + ((size_t)((b << 14) + hw0 + row)) * 160 + qq * 8) = v;
    }
}

// ---------------- weight repack: fp32 -> Wrep[tap][oc][ic] bf16 ------------
__global__ __launch_bounds__(256) void repack_k(const float* __restrict__ w,
                                                unsigned short* __restrict__ wr,
                                                int Cout, int Cin, int OCP, int ICP,
                                                int trans, int n)
{
    int i = blockIdx.x * 256 + threadIdx.x;
    if (i >= n) return;
    int ic = i % ICP, rest = i / ICP;
    int oc = rest % OCP, tap = rest / OCP;
    float v = 0.0f;
    if (oc < Cout && ic < Cin) {
        // conv:  w[oc][ic][kh][kw] OIHW;  convT: w_eff[oc][ic][kh][kw]=w[ic][oc][2-kh][2-kw]
        v = trans ? w[(size_t)(ic * Cout + oc) * 9 + (8 - tap)]
                  : w[(size_t)(oc * Cin + ic) * 9 + tap];
    }
    wr[i] = f2bf(v);
}

// ---------------- zero helpers ----------------
__global__ void zero_k(float* p) { *p = 0.0f; }
__global__ __launch_bounds__(256) void zero4_k(uint4* __restrict__ p, int n4)
{
    int i = blockIdx.x * 256 + threadIdx.x;
    if (i < n4) p[i] = uint4{0, 0, 0, 0};
}

// ---------------- MFMA conv ----------------
// ICP: padded in-channels (buffer stride, mult of 32). K-chunk 32.
// OCB: oc per block (mult 16).
// OMODE 0: NHWC bf16 + relu; 1: NCHW bf16 + relu, oc<OUTC; 2: NCHW fp32 + sigmoid, oc<OUTC.
//
// Input LDS: NB buffers, linear [chunk c 0..1295] 16B (pixel p=c>>2, slot m=c&3),
//   slot m holds k-quad q = m ^ ((p>>1)&3); read byte (p<<6)^(quad<<4)^((p&6)<<3).
// Weight LDS: [tap][oc][slot m] 16B, slot m holds k-quad q = m ^ ((oc>>1)&3);
//   read byte tap*OCB*64 + oc*64 + (quad^((oc>>1)&3))*16. Both patterns: 8 banks,
//   2-way within 16-lane group (free, m136; input variant measured 0 conflicts R3-R8).
template <int ICP, int OCB, int OMODE, int OUTC>
__global__ __launch_bounds__(256, 2) void conv_mfma(const unsigned short* __restrict__ in,
                                                    const unsigned short* __restrict__ wrep,
                                                    const float* __restrict__ bias,
                                                    void* __restrict__ outv, int OCP,
                                                    const unsigned short* __restrict__ zpad)
{
    constexpr int NOT = OCB / 16;
    constexpr int NPH = ICP / 32;
    constexpr int NB  = (NPH > 1) ? 2 : 1;
    constexpr int WCH = 9 * OCB * 4;                 // weight 16B chunks per phase
    __shared__ unsigned short tile[NB][1296 * 8];    // 20736 B per buffer
    __shared__ unsigned short wlds[WCH * 8];         // 36864 B @ OCB=64

    const int tid  = threadIdx.x;
    const int lane = tid & 63, wave = tid >> 6;
    const int col  = lane & 15, quad = lane >> 4;
    const int qsh  = quad << 4;
    const int ocblk = blockIdx.x, tix = blockIdx.y, b = blockIdx.z;
    const int h0 = (tix >> 3) << 4, w0 = (tix & 7) << 4;

    floatx4 acc[NOT][4];
    #pragma unroll
    for (int i = 0; i < NOT; ++i)
        #pragma unroll
        for (int r = 0; r < 4; ++r) acc[i][r] = floatx4{0.f, 0.f, 0.f, 0.f};

    // per-thread source offsets for input gload_lds slots s=0..4 (chunk c = tid + s*256)
    int goff[5];
    #pragma unroll
    for (int s = 0; s < 5; ++s) {
        int c = tid + (s << 8);
        int p = c >> 2, m = c & 3;
        int q = m ^ ((p >> 1) & 3);           // source-side swizzle
        int pr = p / 18, pc = p - pr * 18;
        int gh = h0 - 1 + pr, gw = w0 - 1 + pc;
        bool ok = ((unsigned)gh < 128u) & ((unsigned)gw < 128u);
        goff[s] = ok ? ((((b << 7) + gh) << 7) + gw) * ICP + (q << 3) : -1;
    }

    auto stage_in = [&](int bufi, int icc) {
        unsigned short* base = &tile[bufi][wave * 512];
        #pragma unroll
        for (int s = 0; s < 5; ++s) {
            const unsigned short* src =
                (goff[s] >= 0) ? in + (size_t)goff[s] + icc * 32 : zpad;
            gload_lds16(src, base + s * 2048);
        }
        // tail: chunks 1280..1295 (pixels 320..323 = row 17, cols 14..17)
        if (tid < 16) {
            int c = 1280 + tid;
            int p = c >> 2, m = c & 3;
            int q = m ^ ((p >> 1) & 3);
            int pc = p - 306;                              // p/18 == 17
            int gh = h0 + 16, gw = w0 - 1 + pc;
            uint4 v = uint4{0, 0, 0, 0};
            if ((unsigned)gh < 128u && (unsigned)gw < 128u)
                v = *(const uint4*)(in +
                    (size_t)((((b << 7) + gh) << 7) + gw) * ICP + icc * 32 + (q << 3));
            *(uint4*)(&tile[bufi][c << 3]) = v;
        }
    };

    // weight stage: chunk c = tap*(OCB*4) + oc*4 + m; linear LDS dest, swizzled src.
    auto stage_w = [&](int icc) {
        #pragma unroll
        for (int s = 0; s < (WCH + 255) / 256; ++s) {
            int c = tid + (s << 8);
            bool on = (WCH % 256 == 0) || (c < WCH);   // WCH mult of 64 -> wave-uniform
            if (on) {
                int tap = c / (OCB * 4);
                int rest = c - tap * (OCB * 4);
                int oc = rest >> 2, m = rest & 3;
                int q = m ^ ((oc >> 1) & 3);
                const unsigned short* src = wrep +
                    ((size_t)(tap * OCP + ocblk * OCB + oc)) * ICP + icc * 32 + (q << 3);
                gload_lds16(src, &wlds[(size_t)((s << 8) + wave * 64) * 8]);
            }
        }
    };

    const int aswz = (col << 6) + ((quad ^ ((col >> 1) & 3)) << 4);  // weight read base

    auto compute_ph = [&](int bufi) {
        const unsigned short* tb = &tile[bufi][0];
        #pragma unroll
        for (int tap = 0; tap < 9; ++tap) {
            const int dh = tap / 3, dw = tap % 3;
            bf16x8 bfr[4];
            #pragma unroll
            for (int rt = 0; rt < 4; ++rt) {
                int p = ((wave << 2) + rt + dh) * 18 + col + dw;
                int boff = (p << 6) ^ qsh ^ ((p & 6) << 3);
                bfr[rt] = *(const bf16x8*)((const char*)tb + boff);
            }
            #pragma unroll
            for (int ot = 0; ot < NOT; ++ot) {
                bf16x8 afr = *(const bf16x8*)((const char*)wlds +
                    tap * (OCB * 64) + (ot << 10) + aswz);
                #pragma unroll
                for (int rt = 0; rt < 4; ++rt)
                    acc[ot][rt] = __builtin_amdgcn_mfma_f32_16x16x32_bf16(
                        afr, bfr[rt], acc[ot][rt], 0, 0, 0);
            }
        }
    };

    // ---- pipeline ----
    stage_in(0, 0);
    stage_w(0);
    asm volatile("s_waitcnt vmcnt(0)" ::: "memory");
    __syncthreads();
    #pragma unroll
    for (int icc = 0; icc < NPH; ++icc) {
        const int cur = icc & 1;
        if (icc + 1 < NPH) stage_in(cur ^ 1, icc + 1);   // async, hidden under compute
        compute_ph(cur);                                 // pure LDS + MFMA
        if (icc + 1 < NPH) {
            __syncthreads();                             // all wlds reads done
            stage_w(icc + 1);                            // ~600cyc exposed, x(NPH-1)
            asm volatile("s_waitcnt vmcnt(0)" ::: "memory");
            __syncthreads();                             // weights + next input visible
        }
    }

    // epilogue. D: col=pixel w, row m = quad*4+reg = oc_local
    const int w = w0 + col;
    #pragma unroll
    for (int ot = 0; ot < NOT; ++ot) {
        int oc0 = ocblk * OCB + (ot << 4) + (quad << 2);
        #pragma unroll
        for (int rt = 0; rt < 4; ++rt) {
            int h = h0 + (wave << 2) + rt;
            if constexpr (OMODE == 0) {
                unsigned short* outp = (unsigned short*)outv;
                unsigned short pk[4];
                #pragma unroll
                for (int g = 0; g < 4; ++g) {
                    float vv = acc[ot][rt][g] + bias[oc0 + g];
                    pk[g] = f2bf(fmaxf(vv, 0.0f));
                }
                size_t off = ((size_t)(((b << 7) + h) << 7) + w) * OUTC + oc0;
                *(uint2*)(outp + off) = *(const uint2*)pk;   // 4 consecutive oc, 8B
            } else if constexpr (OMODE == 1) {
                unsigned short* outp = (unsigned short*)outv;
                #pragma unroll
                for (int g = 0; g < 4; ++g) {
                    int oc = oc0 + g;
                    if (oc < OUTC) {
                        float vv = fmaxf(acc[ot][rt][g] + bias[oc], 0.0f);
                        outp[((size_t)(b * OUTC + oc) << 14) + (h << 7) + w] = f2bf(vv);
                    }
                }
            } else {
                float* outp = (float*)outv;
                #pragma unroll
                for (int g = 0; g < 4; ++g) {
                    int oc = oc0 + g;
                    if (oc < OUTC) {
                        float vv = acc[ot][rt][g] + bias[oc];
                        vv = 1.0f / (1.0f + __expf(-vv));
                        outp[((size_t)(b * OUTC + oc) << 14) + (h << 7) + w] = vv;
                    }
                }
            }
        }
    }
}

// ---------------- vector quantizer ----------------
// z3: NCHW bf16 [16,8,128,128]; rows = 8 consecutive flat elements (= 8 w-pixels, one channel).
__global__ __launch_bounds__(256) void vq_k(const unsigned short* __restrict__ z,
                                            const float* __restrict__ emb,
                                            unsigned short* __restrict__ q,
                                            float* __restrict__ loss)
{
    __shared__ float se[512 * 8];
    __shared__ float se2[512];
    __shared__ float red[4];

    for (int i = threadIdx.x; i < 4096; i += 256) se[i] = emb[i];
    __syncthreads();
    for (int k = threadIdx.x; k < 512; k += 256) {
        float s = 0.0f;
        #pragma unroll
        for (int j = 0; j < 8; ++j) { float e = se[k * 8 + j]; s += e * e; }
        se2[k] = s;
    }
    __syncthreads();

    int r = blockIdx.x * 256 + threadIdx.x;   // grid sized exactly 262144
    uint4 raw = *(const uint4*)(z + (size_t)r * 8);
    const unsigned short* pr = (const unsigned short*)&raw;
    float zv[8];
    #pragma unroll
    for (int j = 0; j < 8; ++j) zv[j] = bf2f(pr[j]);

    float best = 3.4e38f;
    int bi = 0;
    for (int k = 0; k < 512; ++k) {
        float dot = 0.0f;
        #pragma unroll
        for (int j = 0; j < 8; ++j) dot += se[k * 8 + j] * zv[j];
        float d = se2[k] - 2.0f * dot;
        if (d < best) { best = d; bi = k; }   // strict <: first-min argmin
    }

    // r = ((b*8+c)*128 + h)*16 + wg
    int wg = r & 15, h = (r >> 4) & 127, c = (r >> 11) & 7, b = r >> 14;
    size_t pixbase = ((size_t)(((b << 7) + h) << 7)) + (wg << 3);
    float lsum = 0.0f;
    #pragma unroll
    for (int j = 0; j < 8; ++j) {
        float e = se[bi * 8 + j];
        q[(pixbase + j) * 32 + c] = f2bf(e);
        float df = e - zv[j];
        lsum += df * df;
    }

    for (int o = 32; o > 0; o >>= 1) lsum += __shfl_down(lsum, o, 64);
    int lane = threadIdx.x & 63, wv = threadIdx.x >> 6;
    if (lane == 0) red[wv] = lsum;
    __syncthreads();
    if (threadIdx.x == 0) atomicAdd(loss, red[0] + red[1] + red[2] + red[3]);
}

__global__ void fin_k(const float* __restrict__ loss, float* __restrict__ out)
{
    out[0] = 1.25f * (*loss) / 2097152.0f;
}

// ---------------- launch ----------------
extern "C" void kernel_launch(void* const* d_in, const int* in_sizes, int n_in,
                              void* d_out, int out_size, void* d_ws, size_t ws_size,
                              hipStream_t stream)
{
    const float* x   = (const float*)d_in[0];
    const float* e1w = (const float*)d_in[1];
    const float* e1b = (const float*)d_in[2];
    const float* e2w = (const float*)d_in[3];
    const float* e2b = (const float*)d_in[4];
    const float* e3w = (const float*)d_in[5];
    const float* e3b = (const float*)d_in[6];
    const float* emb = (const float*)d_in[7];
    const float* d1w = (const float*)d_in[8];
    const float* d1b = (const float*)d_in[9];
    const float* d2w = (const float*)d_in[10];
    const float* d2b = (const float*)d_in[11];
    const float* d3w = (const float*)d_in[12];
    const float* d3b = (const float*)d_in[13];
    float* out = (float*)d_out;

    char* ws = (char*)d_ws;
    size_t off = 0;
    auto alloc = [&](size_t bytes) { void* p = ws + off; off += (bytes + 255) & ~size_t(255); return p; };

    float*          loss  = (float*)alloc(4);
    unsigned short* zpad  = (unsigned short*)alloc(512);
    unsigned short* wr_e1 = (unsigned short*)alloc((size_t)9 * 128 * 160 * 2);
    unsigned short* wr_e2 = (unsigned short*)alloc((size_t)9 * 64 * 128 * 2);
    unsigned short* wr_e3 = (unsigned short*)alloc((size_t)9 * 16 * 64 * 2);
    unsigned short* wr_d1 = (unsigned short*)alloc((size_t)9 * 64 * 32 * 2);
    unsigned short* wr_d2 = (unsigned short*)alloc((size_t)9 * 128 * 64 * 2);
    unsigned short* wr_d3 = (unsigned short*)alloc((size_t)9 * 192 * 128 * 2);
    unsigned short* z3    = (unsigned short*)alloc((size_t)16 * 8 * 16384 * 2);
    unsigned short* qb    = (unsigned short*)alloc((size_t)16 * 16384 * 32 * 2);
    unsigned short* S1    = (unsigned short*)alloc((size_t)16 * 16384 * 160 * 2); // xn -> b2 -> b4
    unsigned short* S2    = (unsigned short*)alloc((size_t)16 * 16384 * 128 * 2); // b1 -> b5
    (void)ws_size;

    zero_k<<<1, 1, 0, stream>>>(loss);
    zero4_k<<<1, 256, 0, stream>>>((uint4*)zpad, 32);   // 512B zero pad for OOB gload_lds
    // zero q (padded 32-ch NHWC; channels 8..31 must be 0)
    zero4_k<<<(16 * 16384 * 32 / 8 + 255) / 256, 256, 0, stream>>>((uint4*)qb, 16 * 16384 * 32 / 8);

    xpose_k<<<dim3(256, 16), 256, 0, stream>>>(x, S1);

    auto rp = [&](const float* w, unsigned short* wr, int Cout, int Cin, int OCP, int ICP, int trans) {
        int n = 9 * OCP * ICP;
        repack_k<<<(n + 255) / 256, 256, 0, stream>>>(w, wr, Cout, Cin, OCP, ICP, trans, n);
    };
    rp(e1w, wr_e1, 128, 156, 128, 160, 0);
    rp(e2w, wr_e2,  64, 128,  64, 128, 0);
    rp(e3w, wr_e3,   8,  64,  16,  64, 0);
    rp(d1w, wr_d1,  64,   8,  64,  32, 1);
    rp(d2w, wr_d2, 128,  64, 128,  64, 1);
    rp(d3w, wr_d3, 156, 128, 192, 128, 1);

    // encoder  (ICP, OCB, OMODE, OUTC); grid = (OCP/OCB, 64, 16)
    conv_mfma<160, 64, 0, 128><<<dim3(2, 64, 16), 256, 0, stream>>>(S1, wr_e1, e1b, S2, 128, zpad);
    conv_mfma<128, 64, 0,  64><<<dim3(1, 64, 16), 256, 0, stream>>>(S2, wr_e2, e2b, S1, 64, zpad);
    conv_mfma< 64, 16, 1,   8><<<dim3(1, 64, 16), 256, 0, stream>>>(S1, wr_e3, e3b, z3, 16, zpad);
    // VQ
    vq_k<<<1024, 256, 0, stream>>>(z3, emb, qb, loss);
    // decoder
    conv_mfma< 32, 64, 0,  64><<<dim3(1, 64, 16), 256, 0, stream>>>(qb, wr_d1, d1b, S1, 64, zpad);
    conv_mfma< 64, 64, 0, 128><<<dim3(2, 64, 16), 256, 0, stream>>>(S1, wr_d2, d2b, S2, 128, zpad);
    conv_mfma<128, 64, 2, 156><<<dim3(3, 64, 16), 256, 0, stream>>>(S2, wr_d3, d3b, out, 192, zpad);

    fin_k<<<1, 1, 0, stream>>>(loss, out + (size_t)16 * 156 * 16384);
}